// Round 2
// baseline (763.065 us; speedup 1.0000x reference)
//
#include <hip/hip_runtime.h>

// ---------------------------------------------------------------------------
// QueryConditionedTransportScorerV3 on MI355X (gfx950)
// Q=64 W=16 A=64 D=H=512.
//   fused@rw1 = Ya[w,a] + Yq[q] + [a*q ; |a-q|+c] @ (rg*rw1)[1024:2048] (MFMA)
//   h = rstd*(sum - mu*S1) + (rb1 + rb@rw1); gelu; @rw2; softmax+entropy fused
// Round 2: K-chunked LDS (2 blk/CU), LN stats folded into build, fast erf,
//          fused pre-kernels.
// ---------------------------------------------------------------------------

#define DEV static __device__ __forceinline__

typedef __attribute__((ext_vector_type(8))) __bf16 bf16x8;
typedef __attribute__((ext_vector_type(4))) float f32x4;

DEV unsigned short f2bf(float f) {
  unsigned u = __builtin_bit_cast(unsigned, f);
  u = (u + 0x7fffu + ((u >> 16) & 1u)) >> 16;
  return (unsigned short)u;
}

// branch-free erf (Abramowitz-Stegun 7.1.26, |err| <= 1.5e-7)
DEV float gelu_fast(float x) {
  const float y = x * 0.70710678118654752f;
  const float z = fabsf(y);
  const float t = __fdividef(1.0f, 1.0f + 0.3275911f * z);
  float p = 1.061405429f;
  p = p * t - 1.453152027f;
  p = p * t + 1.421413741f;
  p = p * t - 0.284496736f;
  p = p * t + 0.254829592f;
  const float e = 1.0f - p * t * __expf(-z * z);
  const float erfv = copysignf(e, y);
  return 0.5f * x * (1.0f + erfv);
}

// ---------------- transpose + bf16-convert rw1 rows 1024..2047 --------------
// WT[n][k2] = rg[1024+k2] * rw1[1024+k2][n],  n in [0,512), k2 in [0,1024)
__global__ __launch_bounds__(256) void wt_kernel(const float* __restrict__ rw1,
                                                 const float* __restrict__ rg,
                                                 unsigned short* __restrict__ WT) {
  __shared__ float t[64][65];
  const int tid = threadIdx.x;
  const int kt = (blockIdx.x >> 3) << 6;   // 16 k-tiles
  const int ct = (blockIdx.x & 7) << 6;    // 8 n-tiles
  for (int idx = tid; idx < 4096; idx += 256) {
    const int r = idx >> 6, c = idx & 63;
    t[r][c] = rg[1024 + kt + r] * rw1[(1024 + kt + r) * 512 + ct + c];
  }
  __syncthreads();
  for (int idx = tid; idx < 4096; idx += 256) {
    const int c = idx >> 6, r = idx & 63;
    WT[(ct + c) * 1024 + kt + r] = f2bf(t[r][c]);
  }
}

// ------------- S1[n] = sum_k rg[k]*rw1[k][n];  B1[n] = sum_k rb[k]*rw1[k][n]
__global__ __launch_bounds__(512) void s1b1_kernel(const float* __restrict__ rw1,
                                                   const float* __restrict__ rg,
                                                   const float* __restrict__ rb,
                                                   float* __restrict__ S1,
                                                   float* __restrict__ B1) {
  const int n = threadIdx.x;
  const int kc = blockIdx.x << 7;
  float s = 0.f, bb = 0.f;
  for (int k = kc; k < kc + 128; ++k) {
    const float wv = rw1[(k << 9) + n];
    s += rg[k] * wv;
    bb += rb[k] * wv;
  }
  atomicAdd(&S1[n], s);
  atomicAdd(&B1[n], bb);
}

// -------- fused q-path: pool -> LN -> lin+gelu -> lin -> qh, Yq -------------
__global__ __launch_bounds__(512) void qpath_kernel(
    const float* __restrict__ qa, const float* __restrict__ qm,
    const float* __restrict__ qg, const float* __restrict__ qb,
    const float* __restrict__ qw1, const float* __restrict__ qb1,
    const float* __restrict__ qw2, const float* __restrict__ qb2,
    const float* __restrict__ rg, const float* __restrict__ rw1,
    float* __restrict__ qh_out, float* __restrict__ yq_out) {
  __shared__ float xs[512], hs[512], qms[64], red[20];
  const int tid = threadIdx.x, l = tid & 63, wv = tid >> 6;
  const int q = blockIdx.x;

  if (wv == 0) {
    float m = fmaxf(qm[(q << 6) + l], 0.f);
    qms[l] = m;
    float s = m;
#pragma unroll
    for (int off = 1; off < 64; off <<= 1) s += __shfl_xor(s, off);
    if (l == 0) red[16] = 1.0f / fmaxf(s, 1e-8f);
  }
  __syncthreads();
  const float sinv = red[16];
  float v = 0.f;
  const float* qaq = qa + (q << 15) + tid;
#pragma unroll 8
  for (int a = 0; a < 64; ++a) v += qms[a] * qaq[a << 9];
  v *= sinv;
  // block LN reduce
  float s = v, ss = v * v;
#pragma unroll
  for (int off = 1; off < 64; off <<= 1) {
    s += __shfl_xor(s, off); ss += __shfl_xor(ss, off);
  }
  if (l == 0) { red[wv] = s; red[8 + wv] = ss; }
  __syncthreads();
  float st = 0.f, sst = 0.f;
#pragma unroll
  for (int i = 0; i < 8; ++i) { st += red[i]; sst += red[8 + i]; }
  const float mu = st * (1.0f / 512.0f);
  const float var = sst * (1.0f / 512.0f) - mu * mu;
  const float rstd = rsqrtf(var + 1e-5f);
  xs[tid] = (v - mu) * rstd * qg[tid] + qb[tid];
  __syncthreads();
  // layer1
  float a1 = qb1[tid];
#pragma unroll 4
  for (int k = 0; k < 512; ++k) a1 += xs[k] * qw1[(k << 9) + tid];
  hs[tid] = gelu_fast(a1);
  __syncthreads();
  // layer2
  float a2 = qb2[tid];
#pragma unroll 4
  for (int k = 0; k < 512; ++k) a2 += hs[k] * qw2[(k << 9) + tid];
  qh_out[(q << 9) + tid] = a2;
  __syncthreads();          // all reads of hs done
  hs[tid] = a2 * rg[512 + tid];
  __syncthreads();
  // Yq = ys @ rw1[512:1024]
  float y = 0.f;
#pragma unroll 4
  for (int k = 0; k < 512; ++k) y += hs[k] * rw1[((512 + k) << 9) + tid];
  yq_out[(q << 9) + tid] = y;
}

// -------- fused atoms-path: LN -> lin+gelu -> lin -> ahh, Ya (8 rows/block) -
__global__ __launch_bounds__(512) void apath_kernel(
    const float* __restrict__ ca, const float* __restrict__ ag,
    const float* __restrict__ ab, const float* __restrict__ aw1,
    const float* __restrict__ ab1, const float* __restrict__ aw2,
    const float* __restrict__ ab2, const float* __restrict__ rg,
    const float* __restrict__ rw1, float* __restrict__ ah_out,
    float* __restrict__ ya_out) {
  __shared__ float xT[4096];   // [k][8]
  __shared__ float hT[4096];   // [k][8]
  const int tid = threadIdx.x, l = tid & 63, wv = tid >> 6;
  const int row0 = blockIdx.x << 3;

  for (int idx = tid; idx < 4096; idx += 512) {
    const int r = idx >> 9, k = idx & 511;
    xT[(k << 3) + r] = ca[((row0 + r) << 9) + k];
  }
  __syncthreads();
  // LN: wave wv -> row wv
  {
    float s = 0.f, ss = 0.f;
    for (int k = l; k < 512; k += 64) {
      const float v = xT[(k << 3) + wv];
      s += v; ss += v * v;
    }
#pragma unroll
    for (int off = 1; off < 64; off <<= 1) {
      s += __shfl_xor(s, off); ss += __shfl_xor(ss, off);
    }
    const float mu = s * (1.0f / 512.0f);
    const float var = ss * (1.0f / 512.0f) - mu * mu;
    const float rstd = rsqrtf(var + 1e-5f);
    for (int k = l; k < 512; k += 64) {
      const int ix = (k << 3) + wv;
      xT[ix] = (xT[ix] - mu) * rstd * ag[k] + ab[k];
    }
  }
  __syncthreads();
  // layer1: col c = tid, 8 rows
  float acc[8] = {};
#pragma unroll 2
  for (int k = 0; k < 512; ++k) {
    const float4 lo = *(const float4*)(xT + (k << 3));
    const float4 hi = *(const float4*)(xT + (k << 3) + 4);
    const float w1 = aw1[(k << 9) + tid];
    acc[0] += lo.x * w1; acc[1] += lo.y * w1; acc[2] += lo.z * w1; acc[3] += lo.w * w1;
    acc[4] += hi.x * w1; acc[5] += hi.y * w1; acc[6] += hi.z * w1; acc[7] += hi.w * w1;
  }
  const float b1v = ab1[tid];
#pragma unroll
  for (int r = 0; r < 8; ++r) hT[(tid << 3) + r] = gelu_fast(acc[r] + b1v);
  __syncthreads();
  // layer2
  float acc2[8] = {};
#pragma unroll 2
  for (int k = 0; k < 512; ++k) {
    const float4 lo = *(const float4*)(hT + (k << 3));
    const float4 hi = *(const float4*)(hT + (k << 3) + 4);
    const float w2 = aw2[(k << 9) + tid];
    acc2[0] += lo.x * w2; acc2[1] += lo.y * w2; acc2[2] += lo.z * w2; acc2[3] += lo.w * w2;
    acc2[4] += hi.x * w2; acc2[5] += hi.y * w2; acc2[6] += hi.z * w2; acc2[7] += hi.w * w2;
  }
  const float b2v = ab2[tid];
  const float rgv = rg[tid];
#pragma unroll
  for (int r = 0; r < 8; ++r) {
    const float o = acc2[r] + b2v;
    ah_out[((row0 + r) << 9) + tid] = o;
    xT[(tid << 3) + r] = o * rgv;        // rg-scaled, transposed for Ya
  }
  __syncthreads();
  // Ya = (ahh*rg) @ rw1[0:512]
  float acc3[8] = {};
#pragma unroll 2
  for (int k = 0; k < 512; ++k) {
    const float4 lo = *(const float4*)(xT + (k << 3));
    const float4 hi = *(const float4*)(xT + (k << 3) + 4);
    const float wr = rw1[(k << 9) + tid];
    acc3[0] += lo.x * wr; acc3[1] += lo.y * wr; acc3[2] += lo.z * wr; acc3[3] += lo.w * wr;
    acc3[4] += hi.x * wr; acc3[5] += hi.y * wr; acc3[6] += hi.z * wr; acc3[7] += hi.w * wr;
  }
#pragma unroll
  for (int r = 0; r < 8; ++r) ya_out[((row0 + r) << 9) + tid] = acc3[r];
}

// -------- fused context-path: concat -> LN -> mlp -> chh (4 rows/block) -----
__global__ __launch_bounds__(512) void cpath_kernel(
    const float* __restrict__ csum, const float* __restrict__ ectx,
    const float* __restrict__ cg, const float* __restrict__ cb,
    const float* __restrict__ cw1, const float* __restrict__ cb1,
    const float* __restrict__ cw2, const float* __restrict__ cb2,
    float* __restrict__ ch_out) {
  __shared__ float xT[4096];   // [k(1024)][4]
  __shared__ float hT[2048];   // [k(512)][4]
  const int tid = threadIdx.x, l = tid & 63, wv = tid >> 6;
  const int row0 = blockIdx.x << 2;

  for (int idx = tid; idx < 4096; idx += 512) {
    const int r = idx >> 10, k = idx & 1023;
    const float v = (k < 512) ? csum[((row0 + r) << 9) + k]
                              : ectx[((row0 + r) << 9) + (k - 512)];
    xT[(k << 2) + r] = v;
  }
  __syncthreads();
  if (wv < 4) {   // LN: wave wv -> row wv, din=1024
    float s = 0.f, ss = 0.f;
    for (int k = l; k < 1024; k += 64) {
      const float v = xT[(k << 2) + wv];
      s += v; ss += v * v;
    }
#pragma unroll
    for (int off = 1; off < 64; off <<= 1) {
      s += __shfl_xor(s, off); ss += __shfl_xor(ss, off);
    }
    const float mu = s * (1.0f / 1024.0f);
    const float var = ss * (1.0f / 1024.0f) - mu * mu;
    const float rstd = rsqrtf(var + 1e-5f);
    for (int k = l; k < 1024; k += 64) {
      const int ix = (k << 2) + wv;
      xT[ix] = (xT[ix] - mu) * rstd * cg[k] + cb[k];
    }
  }
  __syncthreads();
  float acc[4] = {};
#pragma unroll 2
  for (int k = 0; k < 1024; ++k) {
    const float4 xv = *(const float4*)(xT + (k << 2));
    const float w1 = cw1[(k << 9) + tid];
    acc[0] += xv.x * w1; acc[1] += xv.y * w1; acc[2] += xv.z * w1; acc[3] += xv.w * w1;
  }
  const float b1v = cb1[tid];
#pragma unroll
  for (int r = 0; r < 4; ++r) hT[(tid << 2) + r] = gelu_fast(acc[r] + b1v);
  __syncthreads();
  float acc2[4] = {};
#pragma unroll 2
  for (int k = 0; k < 512; ++k) {
    const float4 xv = *(const float4*)(hT + (k << 2));
    const float w2 = cw2[(k << 9) + tid];
    acc2[0] += xv.x * w2; acc2[1] += xv.y * w2; acc2[2] += xv.z * w2; acc2[3] += xv.w * w2;
  }
  const float b2v = cb2[tid];
#pragma unroll
  for (int r = 0; r < 4; ++r) ch_out[((row0 + r) << 9) + tid] = acc2[r] + b2v;
}

// ---------------------------- main fused kernel -----------------------------
// 1 block per (q,w). Two K=512 chunks: build 64x512 bf16 pair tile in LDS
// (frag order, 64 KB), MFMA vs WT; LN stats folded into build. 2 blocks/CU.
__global__ __launch_bounds__(512, 4) void main_kernel(
    const float* __restrict__ AH, const float* __restrict__ QH,
    const float* __restrict__ CH, const unsigned short* __restrict__ WT,
    const float* __restrict__ Ya, const float* __restrict__ Yq,
    const float* __restrict__ S1, const float* __restrict__ B1,
    const float* __restrict__ rb1, const float* __restrict__ rw2,
    const float* __restrict__ rb2, const float* __restrict__ cmass,
    float* __restrict__ out) {
  extern __shared__ char smem_raw[];
  float* qs = (float*)smem_raw;          // 512
  float* cs = qs + 512;                  // 512
  float* s1_s = cs + 512;                // 64
  float* s2_s = s1_s + 64;               // 64
  float* rel_s = s2_s + 64;              // 64
  float* misc = rel_s + 64;              // 2 (+pad)
  uint4* apv = (uint4*)(smem_raw + 5120);  // 64 KB: [ksl(16)][256] uint4

  const int tid = threadIdx.x;
  const int l = tid & 63;
  const int wv = tid >> 6;
  const int q = blockIdx.x >> 4;
  const int w = blockIdx.x & 15;

  qs[tid] = QH[(q << 9) + tid];
  cs[tid] = CH[(w << 9) + tid];
  if (tid < 64) { s1_s[tid] = 0.f; s2_s[tid] = 0.f; rel_s[tid] = 0.f; }
  __syncthreads();

  const int rloc = ((wv & 3) << 4) + (l & 15);
  const float* arow = AH + (((w << 6) + rloc) << 9);
  const int kh = (l >> 4) << 3;          // 0,8,16,24
  const int par = wv >> 2;               // ks parity
  float s1a = 0.f, s2a = 0.f;

  f32x4 acc[4][4] = {};
  const int ncb = (wv << 6) + (l & 15);
  const unsigned short* wbase = WT + ncb * 1024 + kh;

#pragma unroll
  for (int chunk = 0; chunk < 2; ++chunk) {
    // ---- build chunk (rows via wv&3/l&15, ks parity via wv>>2, kh via l>>4)
#pragma unroll
    for (int i = 0; i < 8; ++i) {
      const int ksl = par + (i << 1);
      const int ka = (ksl << 5) + kh;
      const float4 a0 = *(const float4*)(arow + ka);
      const float4 a1 = *(const float4*)(arow + ka + 4);
      const float4 q0 = *(const float4*)(qs + ka);
      const float4 q1 = *(const float4*)(qs + ka + 4);
      const float av[8] = {a0.x, a0.y, a0.z, a0.w, a1.x, a1.y, a1.z, a1.w};
      const float qv[8] = {q0.x, q0.y, q0.z, q0.w, q1.x, q1.y, q1.z, q1.w};
      float vv[8];
      if (chunk == 0) {
#pragma unroll
        for (int j = 0; j < 8; ++j) {
          const float aq = av[j] * qv[j];
          vv[j] = aq;
          s1a += av[j] + aq;
          s2a += av[j] * av[j] + aq * aq;
        }
      } else {
        const float4 c0 = *(const float4*)(cs + ka);
        const float4 c1 = *(const float4*)(cs + ka + 4);
        const float cv[8] = {c0.x, c0.y, c0.z, c0.w, c1.x, c1.y, c1.z, c1.w};
#pragma unroll
        for (int j = 0; j < 8; ++j) {
          const float dd = fabsf(av[j] - qv[j]) + cv[j];
          vv[j] = dd;
          s1a += dd;
          s2a += dd * dd;
        }
      }
      union { unsigned short us[8]; uint4 u4; } pk;
#pragma unroll
      for (int j = 0; j < 8; ++j) pk.us[j] = f2bf(vv[j]);
      apv[(ksl << 8) + ((wv & 3) << 6) + l] = pk.u4;
    }

    if (chunk == 1) {
      // fold per-thread stats into per-row LDS totals
      s1a += __shfl_xor(s1a, 16); s1a += __shfl_xor(s1a, 32);
      s2a += __shfl_xor(s2a, 16); s2a += __shfl_xor(s2a, 32);
      if ((l >> 4) == 0) {
        atomicAdd(&s1_s[rloc], s1a);
        atomicAdd(&s2_s[rloc], s2a);
      }
      if (wv == 0) {  // q-segment stats (shared by all rows)
        float sq = 0.f, sqq = 0.f;
#pragma unroll
        for (int it = 0; it < 8; ++it) {
          const float vq = qs[l + (it << 6)];
          sq += vq; sqq += vq * vq;
        }
#pragma unroll
        for (int off = 1; off < 64; off <<= 1) {
          sq += __shfl_xor(sq, off); sqq += __shfl_xor(sqq, off);
        }
        if (l == 0) { misc[0] = sq; misc[1] = sqq; }
      }
    }
    __syncthreads();

    // ---- MFMA this chunk: wave wv owns cols wv*64..+63
    const int cb = chunk << 9;
#pragma unroll
    for (int ksl = 0; ksl < 16; ++ksl) {
      bf16x8 bfr[4], afr[4];
#pragma unroll
      for (int cf = 0; cf < 4; ++cf)
        bfr[cf] = __builtin_bit_cast(
            bf16x8, *(const uint4*)(wbase + (cf << 14) + cb + (ksl << 5)));
#pragma unroll
      for (int fr = 0; fr < 4; ++fr)
        afr[fr] = __builtin_bit_cast(bf16x8, apv[(ksl << 8) + (fr << 6) + l]);
#pragma unroll
      for (int fr = 0; fr < 4; ++fr)
#pragma unroll
        for (int cf = 0; cf < 4; ++cf)
          acc[fr][cf] = __builtin_amdgcn_mfma_f32_16x16x32_bf16(
              afr[fr], bfr[cf], acc[fr][cf], 0, 0, 0);
    }
    if (chunk == 0) __syncthreads();   // apv reused by next build
  }

  // ---- epilogue: LN-fold + gelu + dot(rw2) -> per-row relevance
  {
    const float sqt = misc[0], sqqt = misc[1];
    float yqv[4], s1c[4], b1c[4], w2c[4];
#pragma unroll
    for (int cf = 0; cf < 4; ++cf) {
      const int n = ncb + (cf << 4);
      yqv[cf] = Yq[(q << 9) + n];
      s1c[cf] = S1[n];
      b1c[cf] = B1[n] + rb1[n];
      w2c[cf] = rw2[n];
    }
    const float* yab = Ya + (w << 15) + ncb;
    const int rsub = (l >> 4) << 2;
#pragma unroll
    for (int fr = 0; fr < 4; ++fr) {
#pragma unroll
      for (int j = 0; j < 4; ++j) {
        const int r = (fr << 4) + rsub + j;
        const float s1r = s1_s[r] + sqt;
        const float s2r = s2_s[r] + sqqt;
        const float mu = s1r * (1.0f / 2048.0f);
        const float rs = rsqrtf(s2r * (1.0f / 2048.0f) - mu * mu + 1e-5f);
        float rp = 0.f;
#pragma unroll
        for (int cf = 0; cf < 4; ++cf) {
          const float ya = yab[(r << 9) + (cf << 4)];
          const float hp = rs * (acc[fr][cf][j] + ya + yqv[cf] - mu * s1c[cf]) + b1c[cf];
          rp += gelu_fast(hp) * w2c[cf];
        }
        rp += __shfl_xor(rp, 1); rp += __shfl_xor(rp, 2);
        rp += __shfl_xor(rp, 4); rp += __shfl_xor(rp, 8);
        if ((l & 15) == 0) atomicAdd(&rel_s[r], rp);
      }
    }
  }
  __syncthreads();

  // ---- softmax over atoms + entropy (wave 0)
  if (tid < 64) {
    const float relv = rel_s[tid] + rb2[0];
    const float x = logf(fmaxf(cmass[(w << 6) + tid], 1e-8f)) + relv;
    float m = x;
#pragma unroll
    for (int off = 1; off < 64; off <<= 1) m = fmaxf(m, __shfl_xor(m, off));
    const float p = expf(x - m);
    float s = p;
#pragma unroll
    for (int off = 1; off < 64; off <<= 1) s += __shfl_xor(s, off);
    float mix = p / fmaxf(s, 1e-8f);
    float s2 = mix;
#pragma unroll
    for (int off = 1; off < 64; off <<= 1) s2 += __shfl_xor(s2, off);
    mix = mix / fmaxf(s2, 1e-8f);
    const float et = -mix * logf(fmaxf(mix, 1e-8f));
    float ent = et;
#pragma unroll
    for (int off = 1; off < 64; off <<= 1) ent += __shfl_xor(ent, off);
    out[(blockIdx.x << 6) + tid] = mix;                 // mixed[q][w][a]
    if (tid == 0) out[65536 + blockIdx.x] = ent;        // entropy[q][w]
  }
}

// ---------------------------------------------------------------------------
extern "C" void kernel_launch(void* const* d_in, const int* in_sizes, int n_in,
                              void* d_out, int out_size, void* d_ws, size_t ws_size,
                              hipStream_t stream) {
  (void)in_sizes; (void)n_in; (void)out_size; (void)ws_size;
  const float* q_atoms = (const float*)d_in[0];
  const float* q_mass  = (const float*)d_in[1];
  const float* c_atoms = (const float*)d_in[2];
  const float* c_mass  = (const float*)d_in[3];
  const float* c_sum   = (const float*)d_in[4];
  const float* e_ctx   = (const float*)d_in[5];
  const float* qg  = (const float*)d_in[6];  const float* qb  = (const float*)d_in[7];
  const float* qw1 = (const float*)d_in[8];  const float* qb1 = (const float*)d_in[9];
  const float* qw2 = (const float*)d_in[10]; const float* qb2 = (const float*)d_in[11];
  const float* ag  = (const float*)d_in[12]; const float* ab  = (const float*)d_in[13];
  const float* aw1 = (const float*)d_in[14]; const float* ab1 = (const float*)d_in[15];
  const float* aw2 = (const float*)d_in[16]; const float* ab2 = (const float*)d_in[17];
  const float* cg  = (const float*)d_in[18]; const float* cb  = (const float*)d_in[19];
  const float* cw1 = (const float*)d_in[20]; const float* cb1 = (const float*)d_in[21];
  const float* cw2 = (const float*)d_in[22]; const float* cb2 = (const float*)d_in[23];
  const float* rg  = (const float*)d_in[24]; const float* rb  = (const float*)d_in[25];
  const float* rw1 = (const float*)d_in[26]; const float* rb1 = (const float*)d_in[27];
  const float* rw2 = (const float*)d_in[28]; const float* rb2 = (const float*)d_in[29];

  float* ws = (float*)d_ws;
  float* qh  = ws;                          // 32768
  float* ahh = ws + 32768;                  // 524288
  float* chh = ws + 557056;                 // 8192
  float* Ya  = ws + 565248;                 // 524288
  float* Yq  = ws + 1089536;                // 32768
  float* S1  = ws + 1122304;                // 512
  float* B1  = ws + 1122816;                // 512
  unsigned short* WT = (unsigned short*)(ws + 1123328);  // 524288 bf16 = 1 MB
  float* out = (float*)d_out;

  hipMemsetAsync(S1, 0, 1024 * sizeof(float), stream);   // S1 + B1
  wt_kernel<<<128, 256, 0, stream>>>(rw1, rg, WT);
  s1b1_kernel<<<16, 512, 0, stream>>>(rw1, rg, rb, S1, B1);
  qpath_kernel<<<64, 512, 0, stream>>>(q_atoms, q_mass, qg, qb, qw1, qb1, qw2, qb2,
                                       rg, rw1, qh, Yq);
  apath_kernel<<<128, 512, 0, stream>>>(c_atoms, ag, ab, aw1, ab1, aw2, ab2,
                                        rg, rw1, ahh, Ya);
  cpath_kernel<<<4, 512, 0, stream>>>(c_sum, e_ctx, cg, cb, cw1, cb1, cw2, cb2, chh);

  static const size_t MAIN_SMEM = 5120 + 65536;  // 70656 B -> 2 blocks/CU
  hipFuncSetAttribute((const void*)main_kernel,
                      hipFuncAttributeMaxDynamicSharedMemorySize, (int)MAIN_SMEM);
  main_kernel<<<1024, 512, MAIN_SMEM, stream>>>(ahh, qh, chh, WT, Ya, Yq, S1, B1,
                                                rb1, rw2, rb2, c_mass, out);
}

// Round 3
// 523.124 us; speedup vs baseline: 1.4587x; 1.4587x over previous
//
#include <hip/hip_runtime.h>

// ---------------------------------------------------------------------------
// QueryConditionedTransportScorerV3 on MI355X (gfx950)
// Q=64 W=16 A=64 D=H=512.
//   fused@rw1 = Ya[w,a] + Yq[q] + [a*q ; |a-q|+c] @ (rg*rw1)[1024:2048] (MFMA)
//   h = rstd*(sum - mu*S1) + (rb1 + rb@rw1); gelu; @rw2; softmax+entropy fused
// Round 3: wide pre-path — 1 prep kernel (352 blk) + 2 FC kernels (276 blk,
//   16-row register tiles, broadcast float4 A-loads), Waya/Wqyq precompute
//   to parallelize Ya/Yq with ahh/qh. Main kernel unchanged.
// ---------------------------------------------------------------------------

#define DEV static __device__ __forceinline__

typedef __attribute__((ext_vector_type(8))) __bf16 bf16x8;
typedef __attribute__((ext_vector_type(4))) float f32x4;

DEV unsigned short f2bf(float f) {
  unsigned u = __builtin_bit_cast(unsigned, f);
  u = (u + 0x7fffu + ((u >> 16) & 1u)) >> 16;
  return (unsigned short)u;
}

// branch-free erf (Abramowitz-Stegun 7.1.26, |err| <= 1.5e-7)
DEV float gelu_fast(float x) {
  const float y = x * 0.70710678118654752f;
  const float z = fabsf(y);
  const float t = __fdividef(1.0f, 1.0f + 0.3275911f * z);
  float p = 1.061405429f;
  p = p * t - 1.453152027f;
  p = p * t + 1.421413741f;
  p = p * t - 0.284496736f;
  p = p * t + 0.254829592f;
  const float e = 1.0f - p * t * __expf(-z * z);
  const float erfv = copysignf(e, y);
  return 0.5f * x * (1.0f + erfv);
}

// ---- ws layout (float offsets) --------------------------------------------
// Ya aliases xa, Yq aliases xq (dead after FC1).
#define OFF_XQ    0          // 64*512
#define OFF_XA    32768      // 1024*512
#define OFF_XC    557056     // 16*1024
#define OFF_HQ    573440     // 64*512
#define OFF_HA    606208     // 1024*512
#define OFF_HC    1130496    // 16*512
#define OFF_QH    1138688    // 64*512
#define OFF_AHH   1171456    // 1024*512
#define OFF_CHH   1695744    // 16*512
#define OFF_YA    OFF_XA
#define OFF_YQ    OFF_XQ
#define OFF_WAYA  1703936    // 512*512
#define OFF_WQYQ  1966080    // 512*512
#define OFF_BYA   2228224    // 512
#define OFF_BYQ   2228736    // 512
#define OFF_S1    2229248    // 512
#define OFF_B1    2229760    // 512
#define OFF_WT    2230272    // 524288 bf16 = 262144 f32  (total 2492416 f32)

// ======================== P0: wide prep kernel ==============================
// roles: [0,128) WT transpose | [128,144) S1/B1 | [144,208) q pool+LN
//        [208,336) a LN (8 rows/blk, wave per row) | [336,352) c concat+LN
__global__ __launch_bounds__(512) void pre0_kernel(
    const float* __restrict__ qa, const float* __restrict__ qm,
    const float* __restrict__ ca, const float* __restrict__ csum,
    const float* __restrict__ ectx,
    const float* __restrict__ qg, const float* __restrict__ qb,
    const float* __restrict__ ag, const float* __restrict__ ab,
    const float* __restrict__ cg, const float* __restrict__ cb,
    const float* __restrict__ rw1, const float* __restrict__ rg,
    const float* __restrict__ rb, float* __restrict__ ws) {
  __shared__ float sh[4160];   // 64*65 floats, reused per role
  const int b = blockIdx.x, tid = threadIdx.x, l = tid & 63, wv = tid >> 6;

  if (b < 128) {
    // ---- WT[n][k2] = rg[1024+k2] * rw1[1024+k2][n]
    unsigned short* WT = (unsigned short*)(ws + OFF_WT);
    float (*t)[65] = (float(*)[65])sh;
    const int kt = (b >> 3) << 6;
    const int ct = (b & 7) << 6;
    for (int idx = tid; idx < 4096; idx += 512) {
      const int r = idx >> 6, c = idx & 63;
      t[r][c] = rg[1024 + kt + r] * rw1[(1024 + kt + r) * 512 + ct + c];
    }
    __syncthreads();
    for (int idx = tid; idx < 4096; idx += 512) {
      const int c = idx >> 6, r = idx & 63;
      WT[(ct + c) * 1024 + kt + r] = f2bf(t[r][c]);
    }
  } else if (b < 144) {
    // ---- S1[n] += sum rg[k]*rw1[k][n]; B1[n] += sum rb[k]*rw1[k][n]
    const int kc = (b - 128) << 7;
    float s0 = 0.f, s1 = 0.f, b0 = 0.f, b1v = 0.f;
    for (int k = kc; k < kc + 128; k += 2) {
      const float wa = rw1[(k << 9) + tid];
      const float wb = rw1[((k + 1) << 9) + tid];
      s0 += rg[k] * wa; b0 += rb[k] * wa;
      s1 += rg[k + 1] * wb; b1v += rb[k + 1] * wb;
    }
    atomicAdd(ws + OFF_S1 + tid, s0 + s1);
    atomicAdd(ws + OFF_B1 + tid, b0 + b1v);
  } else if (b < 208) {
    // ---- q path: masses -> pool -> LN -> xq
    const int q = b - 144;
    if (wv == 0) {
      float m = fmaxf(qm[(q << 6) + l], 0.f);
      sh[l] = m;
      float s = m;
#pragma unroll
      for (int off = 1; off < 64; off <<= 1) s += __shfl_xor(s, off);
      if (l == 0) sh[64] = 1.0f / fmaxf(s, 1e-8f);
    }
    __syncthreads();
    const float sinv = sh[64];
    const float* qaq = qa + (q << 15) + tid;
    float v0 = 0.f, v1 = 0.f, v2 = 0.f, v3 = 0.f;
#pragma unroll 4
    for (int a = 0; a < 64; a += 4) {
      v0 += sh[a] * qaq[a << 9];
      v1 += sh[a + 1] * qaq[(a + 1) << 9];
      v2 += sh[a + 2] * qaq[(a + 2) << 9];
      v3 += sh[a + 3] * qaq[(a + 3) << 9];
    }
    const float v = (v0 + v1 + v2 + v3) * sinv;
    float s = v, ss = v * v;
#pragma unroll
    for (int off = 1; off < 64; off <<= 1) {
      s += __shfl_xor(s, off); ss += __shfl_xor(ss, off);
    }
    if (l == 0) { sh[128 + wv] = s; sh[136 + wv] = ss; }
    __syncthreads();
    float st = 0.f, sst = 0.f;
#pragma unroll
    for (int i = 0; i < 8; ++i) { st += sh[128 + i]; sst += sh[136 + i]; }
    const float mu = st * (1.0f / 512.0f);
    const float rstd = rsqrtf(sst * (1.0f / 512.0f) - mu * mu + 1e-5f);
    ws[OFF_XQ + (q << 9) + tid] = (v - mu) * rstd * qg[tid] + qb[tid];
  } else if (b < 336) {
    // ---- a path LN: wave per row
    const int row = ((b - 208) << 3) + wv;
    const float* crow = ca + (row << 9);
    float x[8];
    float s = 0.f, ss = 0.f;
#pragma unroll
    for (int i = 0; i < 8; ++i) {
      x[i] = crow[l + (i << 6)];
      s += x[i]; ss += x[i] * x[i];
    }
#pragma unroll
    for (int off = 1; off < 64; off <<= 1) {
      s += __shfl_xor(s, off); ss += __shfl_xor(ss, off);
    }
    const float mu = s * (1.0f / 512.0f);
    const float rstd = rsqrtf(ss * (1.0f / 512.0f) - mu * mu + 1e-5f);
#pragma unroll
    for (int i = 0; i < 8; ++i) {
      const int k = l + (i << 6);
      ws[OFF_XA + (row << 9) + k] = (x[i] - mu) * rstd * ag[k] + ab[k];
    }
  } else {
    // ---- c path: concat + LN (din=1024)
    const int w = b - 336;
    const float v0 = csum[(w << 9) + tid];
    const float v1 = ectx[(w << 9) + tid];
    float s = v0 + v1, ss = v0 * v0 + v1 * v1;
#pragma unroll
    for (int off = 1; off < 64; off <<= 1) {
      s += __shfl_xor(s, off); ss += __shfl_xor(ss, off);
    }
    if (l == 0) { sh[wv] = s; sh[8 + wv] = ss; }
    __syncthreads();
    float st = 0.f, sst = 0.f;
#pragma unroll
    for (int i = 0; i < 8; ++i) { st += sh[i]; sst += sh[8 + i]; }
    const float mu = st * (1.0f / 1024.0f);
    const float rstd = rsqrtf(sst * (1.0f / 1024.0f) - mu * mu + 1e-5f);
    ws[OFF_XC + (w << 10) + tid] = (v0 - mu) * rstd * cg[tid] + cb[tid];
    ws[OFF_XC + (w << 10) + 512 + tid] =
        (v1 - mu) * rstd * cg[512 + tid] + cb[512 + tid];
  }
}

// ======================== generic FC tile ===================================
// 256 threads: c = ct*128 + tid%128, rg = tid/128; RPT rows per thread.
// out[r][c] = (gelu?)( bias[c] + sum_k A[r][k] * (s?s[k]:1) * W[k][c] )
template <int RPT, bool GELU, bool HAS_S, bool SROW>
DEV void fc_tile(const float* __restrict__ A, int lda,
                 const float* __restrict__ W, const float* __restrict__ bias,
                 const float* __restrict__ s, float* __restrict__ O,
                 int K, int rt, int ct, int tid) {
  const int c = (ct << 7) + (tid & 127);
  const int rg = tid >> 7;
  const int r0 = SROW ? 0 : rt * (2 * RPT) + rg * RPT;
  float acc[RPT];
#pragma unroll
  for (int j = 0; j < RPT; ++j) acc[j] = 0.f;
  for (int k0 = 0; k0 < K; k0 += 4) {
    float w0 = W[(k0 + 0) * 512 + c];
    float w1 = W[(k0 + 1) * 512 + c];
    float w2 = W[(k0 + 2) * 512 + c];
    float w3 = W[(k0 + 3) * 512 + c];
    if (HAS_S) {
      w0 *= s[k0]; w1 *= s[k0 + 1]; w2 *= s[k0 + 2]; w3 *= s[k0 + 3];
    }
#pragma unroll
    for (int j = 0; j < RPT; ++j) {
      const float4 xv = *(const float4*)(A + (r0 + j) * lda + k0);
      acc[j] = fmaf(xv.w, w3, fmaf(xv.z, w2, fmaf(xv.y, w1, fmaf(xv.x, w0, acc[j]))));
    }
  }
  const float bv = bias ? bias[c] : 0.f;
#pragma unroll
  for (int j = 0; j < RPT; ++j) {
    float o = acc[j] + bv;
    if (GELU) o = gelu_fast(o);
    O[(r0 + j) * 512 + c] = o;
  }
}

// ---- FC1: layer1 (a/q/c) + Waya/Wqyq + bya/byq -----------------------------
__global__ __launch_bounds__(256) void fc1_kernel(
    float* __restrict__ ws,
    const float* __restrict__ aw1, const float* __restrict__ ab1,
    const float* __restrict__ qw1, const float* __restrict__ qb1,
    const float* __restrict__ cw1, const float* __restrict__ cb1,
    const float* __restrict__ aw2, const float* __restrict__ qw2,
    const float* __restrict__ ab2, const float* __restrict__ qb2,
    const float* __restrict__ rw1, const float* __restrict__ rg) {
  const int b = blockIdx.x, tid = threadIdx.x;
  if (b < 128) {           // a layer1: 1024 rows
    fc_tile<16, true, false, false>(ws + OFF_XA, 512, aw1, ab1, nullptr,
                                    ws + OFF_HA, 512, b >> 2, b & 3, tid);
  } else if (b < 136) {    // q layer1: 64 rows
    const int bb = b - 128;
    fc_tile<16, true, false, false>(ws + OFF_XQ, 512, qw1, qb1, nullptr,
                                    ws + OFF_HQ, 512, bb >> 2, bb & 3, tid);
  } else if (b < 140) {    // c layer1: 16 rows, K=1024
    fc_tile<8, true, false, false>(ws + OFF_XC, 1024, cw1, cb1, nullptr,
                                   ws + OFF_HC, 1024, 0, b - 136, tid);
  } else if (b < 204) {    // Waya[k][n] = sum_j aw2[k][j]*rg[j]*rw1[j][n]
    const int bb = b - 140;
    fc_tile<16, false, true, false>(aw2, 512, rw1, nullptr, rg,
                                    ws + OFF_WAYA, 512, bb >> 2, bb & 3, tid);
  } else if (b < 268) {    // Wqyq[k][n] = sum_j qw2[k][j]*rg[512+j]*rw1hi[j][n]
    const int bb = b - 204;
    fc_tile<16, false, true, false>(qw2, 512, rw1 + 512 * 512, nullptr, rg + 512,
                                    ws + OFF_WQYQ, 512, bb >> 2, bb & 3, tid);
  } else if (b < 272) {    // bya[n] = sum_j ab2[j]*rg[j]*rw1[j][n]
    fc_tile<1, false, true, true>(ab2, 0, rw1, nullptr, rg,
                                  ws + OFF_BYA, 512, 0, b - 268, tid);
  } else {                 // byq[n] = sum_j qb2[j]*rg[512+j]*rw1hi[j][n]
    fc_tile<1, false, true, true>(qb2, 0, rw1 + 512 * 512, nullptr, rg + 512,
                                  ws + OFF_BYQ, 512, 0, b - 272, tid);
  }
}

// ---- FC2: layer2 (ahh/qh/chh) + Ya/Yq (via Waya/Wqyq) ----------------------
__global__ __launch_bounds__(256) void fc2_kernel(
    float* __restrict__ ws,
    const float* __restrict__ aw2, const float* __restrict__ ab2,
    const float* __restrict__ qw2, const float* __restrict__ qb2,
    const float* __restrict__ cw2, const float* __restrict__ cb2) {
  const int b = blockIdx.x, tid = threadIdx.x;
  if (b < 128) {           // ahh = ha @ aw2 + ab2
    fc_tile<16, false, false, false>(ws + OFF_HA, 512, aw2, ab2, nullptr,
                                     ws + OFF_AHH, 512, b >> 2, b & 3, tid);
  } else if (b < 256) {    // Ya = ha @ Waya + bya
    const int bb = b - 128;
    fc_tile<16, false, false, false>(ws + OFF_HA, 512, ws + OFF_WAYA,
                                     ws + OFF_BYA, nullptr, ws + OFF_YA, 512,
                                     bb >> 2, bb & 3, tid);
  } else if (b < 264) {    // qh = hq @ qw2 + qb2
    const int bb = b - 256;
    fc_tile<16, false, false, false>(ws + OFF_HQ, 512, qw2, qb2, nullptr,
                                     ws + OFF_QH, 512, bb >> 2, bb & 3, tid);
  } else if (b < 272) {    // Yq = hq @ Wqyq + byq
    const int bb = b - 264;
    fc_tile<16, false, false, false>(ws + OFF_HQ, 512, ws + OFF_WQYQ,
                                     ws + OFF_BYQ, nullptr, ws + OFF_YQ, 512,
                                     bb >> 2, bb & 3, tid);
  } else {                 // chh = hc @ cw2 + cb2
    fc_tile<8, false, false, false>(ws + OFF_HC, 512, cw2, cb2, nullptr,
                                    ws + OFF_CHH, 512, 0, b - 272, tid);
  }
}

// ---------------------------- main fused kernel -----------------------------
// 1 block per (q,w). Two K=512 chunks: build 64x512 bf16 pair tile in LDS
// (frag order, 64 KB), MFMA vs WT; LN stats folded into build. 2 blocks/CU.
__global__ __launch_bounds__(512, 4) void main_kernel(
    const float* __restrict__ AH, const float* __restrict__ QH,
    const float* __restrict__ CH, const unsigned short* __restrict__ WT,
    const float* __restrict__ Ya, const float* __restrict__ Yq,
    const float* __restrict__ S1, const float* __restrict__ B1,
    const float* __restrict__ rb1, const float* __restrict__ rw2,
    const float* __restrict__ rb2, const float* __restrict__ cmass,
    float* __restrict__ out) {
  extern __shared__ char smem_raw[];
  float* qs = (float*)smem_raw;          // 512
  float* cs = qs + 512;                  // 512
  float* s1_s = cs + 512;                // 64
  float* s2_s = s1_s + 64;               // 64
  float* rel_s = s2_s + 64;              // 64
  float* misc = rel_s + 64;              // 2 (+pad)
  uint4* apv = (uint4*)(smem_raw + 5120);  // 64 KB: [ksl(16)][256] uint4

  const int tid = threadIdx.x;
  const int l = tid & 63;
  const int wv = tid >> 6;
  const int q = blockIdx.x >> 4;
  const int w = blockIdx.x & 15;

  qs[tid] = QH[(q << 9) + tid];
  cs[tid] = CH[(w << 9) + tid];
  if (tid < 64) { s1_s[tid] = 0.f; s2_s[tid] = 0.f; rel_s[tid] = 0.f; }
  __syncthreads();

  const int rloc = ((wv & 3) << 4) + (l & 15);
  const float* arow = AH + (((w << 6) + rloc) << 9);
  const int kh = (l >> 4) << 3;          // 0,8,16,24
  const int par = wv >> 2;               // ks parity
  float s1a = 0.f, s2a = 0.f;

  f32x4 acc[4][4] = {};
  const int ncb = (wv << 6) + (l & 15);
  const unsigned short* wbase = WT + ncb * 1024 + kh;

#pragma unroll
  for (int chunk = 0; chunk < 2; ++chunk) {
    // ---- build chunk (rows via wv&3/l&15, ks parity via wv>>2, kh via l>>4)
#pragma unroll
    for (int i = 0; i < 8; ++i) {
      const int ksl = par + (i << 1);
      const int ka = (ksl << 5) + kh;
      const float4 a0 = *(const float4*)(arow + ka);
      const float4 a1 = *(const float4*)(arow + ka + 4);
      const float4 q0 = *(const float4*)(qs + ka);
      const float4 q1 = *(const float4*)(qs + ka + 4);
      const float av[8] = {a0.x, a0.y, a0.z, a0.w, a1.x, a1.y, a1.z, a1.w};
      const float qv[8] = {q0.x, q0.y, q0.z, q0.w, q1.x, q1.y, q1.z, q1.w};
      float vv[8];
      if (chunk == 0) {
#pragma unroll
        for (int j = 0; j < 8; ++j) {
          const float aq = av[j] * qv[j];
          vv[j] = aq;
          s1a += av[j] + aq;
          s2a += av[j] * av[j] + aq * aq;
        }
      } else {
        const float4 c0 = *(const float4*)(cs + ka);
        const float4 c1 = *(const float4*)(cs + ka + 4);
        const float cv[8] = {c0.x, c0.y, c0.z, c0.w, c1.x, c1.y, c1.z, c1.w};
#pragma unroll
        for (int j = 0; j < 8; ++j) {
          const float dd = fabsf(av[j] - qv[j]) + cv[j];
          vv[j] = dd;
          s1a += dd;
          s2a += dd * dd;
        }
      }
      union { unsigned short us[8]; uint4 u4; } pk;
#pragma unroll
      for (int j = 0; j < 8; ++j) pk.us[j] = f2bf(vv[j]);
      apv[(ksl << 8) + ((wv & 3) << 6) + l] = pk.u4;
    }

    if (chunk == 1) {
      // fold per-thread stats into per-row LDS totals
      s1a += __shfl_xor(s1a, 16); s1a += __shfl_xor(s1a, 32);
      s2a += __shfl_xor(s2a, 16); s2a += __shfl_xor(s2a, 32);
      if ((l >> 4) == 0) {
        atomicAdd(&s1_s[rloc], s1a);
        atomicAdd(&s2_s[rloc], s2a);
      }
      if (wv == 0) {  // q-segment stats (shared by all rows)
        float sq = 0.f, sqq = 0.f;
#pragma unroll
        for (int it = 0; it < 8; ++it) {
          const float vq = qs[l + (it << 6)];
          sq += vq; sqq += vq * vq;
        }
#pragma unroll
        for (int off = 1; off < 64; off <<= 1) {
          sq += __shfl_xor(sq, off); sqq += __shfl_xor(sqq, off);
        }
        if (l == 0) { misc[0] = sq; misc[1] = sqq; }
      }
    }
    __syncthreads();

    // ---- MFMA this chunk: wave wv owns cols wv*64..+63
    const int cb = chunk << 9;
#pragma unroll
    for (int ksl = 0; ksl < 16; ++ksl) {
      bf16x8 bfr[4], afr[4];
#pragma unroll
      for (int cf = 0; cf < 4; ++cf)
        bfr[cf] = __builtin_bit_cast(
            bf16x8, *(const uint4*)(wbase + (cf << 14) + cb + (ksl << 5)));
#pragma unroll
      for (int fr = 0; fr < 4; ++fr)
        afr[fr] = __builtin_bit_cast(bf16x8, apv[(ksl << 8) + (fr << 6) + l]);
#pragma unroll
      for (int fr = 0; fr < 4; ++fr)
#pragma unroll
        for (int cf = 0; cf < 4; ++cf)
          acc[fr][cf] = __builtin_amdgcn_mfma_f32_16x16x32_bf16(
              afr[fr], bfr[cf], acc[fr][cf], 0, 0, 0);
    }
    if (chunk == 0) __syncthreads();   // apv reused by next build
  }

  // ---- epilogue: LN-fold + gelu + dot(rw2) -> per-row relevance
  {
    const float sqt = misc[0], sqqt = misc[1];
    float yqv[4], s1c[4], b1c[4], w2c[4];
#pragma unroll
    for (int cf = 0; cf < 4; ++cf) {
      const int n = ncb + (cf << 4);
      yqv[cf] = Yq[(q << 9) + n];
      s1c[cf] = S1[n];
      b1c[cf] = B1[n] + rb1[n];
      w2c[cf] = rw2[n];
    }
    const float* yab = Ya + (w << 15) + ncb;
    const int rsub = (l >> 4) << 2;
#pragma unroll
    for (int fr = 0; fr < 4; ++fr) {
#pragma unroll
      for (int j = 0; j < 4; ++j) {
        const int r = (fr << 4) + rsub + j;
        const float s1r = s1_s[r] + sqt;
        const float s2r = s2_s[r] + sqqt;
        const float mu = s1r * (1.0f / 2048.0f);
        const float rs = rsqrtf(s2r * (1.0f / 2048.0f) - mu * mu + 1e-5f);
        float rp = 0.f;
#pragma unroll
        for (int cf = 0; cf < 4; ++cf) {
          const float ya = yab[(r << 9) + (cf << 4)];
          const float hp = rs * (acc[fr][cf][j] + ya + yqv[cf] - mu * s1c[cf]) + b1c[cf];
          rp += gelu_fast(hp) * w2c[cf];
        }
        rp += __shfl_xor(rp, 1); rp += __shfl_xor(rp, 2);
        rp += __shfl_xor(rp, 4); rp += __shfl_xor(rp, 8);
        if ((l & 15) == 0) atomicAdd(&rel_s[r], rp);
      }
    }
  }
  __syncthreads();

  // ---- softmax over atoms + entropy (wave 0)
  if (tid < 64) {
    const float relv = rel_s[tid] + rb2[0];
    const float x = logf(fmaxf(cmass[(w << 6) + tid], 1e-8f)) + relv;
    float m = x;
#pragma unroll
    for (int off = 1; off < 64; off <<= 1) m = fmaxf(m, __shfl_xor(m, off));
    const float p = expf(x - m);
    float s = p;
#pragma unroll
    for (int off = 1; off < 64; off <<= 1) s += __shfl_xor(s, off);
    float mix = p / fmaxf(s, 1e-8f);
    float s2 = mix;
#pragma unroll
    for (int off = 1; off < 64; off <<= 1) s2 += __shfl_xor(s2, off);
    mix = mix / fmaxf(s2, 1e-8f);
    const float et = -mix * logf(fmaxf(mix, 1e-8f));
    float ent = et;
#pragma unroll
    for (int off = 1; off < 64; off <<= 1) ent += __shfl_xor(ent, off);
    out[(blockIdx.x << 6) + tid] = mix;                 // mixed[q][w][a]
    if (tid == 0) out[65536 + blockIdx.x] = ent;        // entropy[q][w]
  }
}

// ---------------------------------------------------------------------------
extern "C" void kernel_launch(void* const* d_in, const int* in_sizes, int n_in,
                              void* d_out, int out_size, void* d_ws, size_t ws_size,
                              hipStream_t stream) {
  (void)in_sizes; (void)n_in; (void)out_size; (void)ws_size;
  const float* q_atoms = (const float*)d_in[0];
  const float* q_mass  = (const float*)d_in[1];
  const float* c_atoms = (const float*)d_in[2];
  const float* c_mass  = (const float*)d_in[3];
  const float* c_sum   = (const float*)d_in[4];
  const float* e_ctx   = (const float*)d_in[5];
  const float* qg  = (const float*)d_in[6];  const float* qb  = (const float*)d_in[7];
  const float* qw1 = (const float*)d_in[8];  const float* qb1 = (const float*)d_in[9];
  const float* qw2 = (const float*)d_in[10]; const float* qb2 = (const float*)d_in[11];
  const float* ag  = (const float*)d_in[12]; const float* ab  = (const float*)d_in[13];
  const float* aw1 = (const float*)d_in[14]; const float* ab1 = (const float*)d_in[15];
  const float* aw2 = (const float*)d_in[16]; const float* ab2 = (const float*)d_in[17];
  const float* cg  = (const float*)d_in[18]; const float* cb  = (const float*)d_in[19];
  const float* cw1 = (const float*)d_in[20]; const float* cb1 = (const float*)d_in[21];
  const float* cw2 = (const float*)d_in[22]; const float* cb2 = (const float*)d_in[23];
  const float* rg  = (const float*)d_in[24]; const float* rb  = (const float*)d_in[25];
  const float* rw1 = (const float*)d_in[26]; const float* rb1 = (const float*)d_in[27];
  const float* rw2 = (const float*)d_in[28]; const float* rb2 = (const float*)d_in[29];

  float* ws = (float*)d_ws;
  float* out = (float*)d_out;

  hipMemsetAsync(ws + OFF_S1, 0, 1024 * sizeof(float), stream);  // S1+B1
  pre0_kernel<<<352, 512, 0, stream>>>(q_atoms, q_mass, c_atoms, c_sum, e_ctx,
                                       qg, qb, ag, ab, cg, cb, rw1, rg, rb, ws);
  fc1_kernel<<<276, 256, 0, stream>>>(ws, aw1, ab1, qw1, qb1, cw1, cb1,
                                      aw2, qw2, ab2, qb2, rw1, rg);
  fc2_kernel<<<276, 256, 0, stream>>>(ws, aw2, ab2, qw2, qb2, cw2, cb2);

  static const size_t MAIN_SMEM = 5120 + 65536;  // 70656 B -> 2 blocks/CU
  hipFuncSetAttribute((const void*)main_kernel,
                      hipFuncAttributeMaxDynamicSharedMemorySize, (int)MAIN_SMEM);
  main_kernel<<<1024, 512, MAIN_SMEM, stream>>>(
      ws + OFF_AHH, ws + OFF_QH, ws + OFF_CHH,
      (const unsigned short*)(ws + OFF_WT), ws + OFF_YA, ws + OFF_YQ,
      ws + OFF_S1, ws + OFF_B1, rb1, rw2, rb2, c_mass, out);
}